// Round 12
// baseline (27.423 us; speedup 1.0000x reference)
//
#include <hip/hip_runtime.h>

typedef float f2 __attribute__((ext_vector_type(2)));
typedef float f4 __attribute__((ext_vector_type(4)));
typedef int   i4 __attribute__((ext_vector_type(4)));

#define HIDDEN 64
#define MASK_FILL -1e9f
#define EPT 4  // edges per thread

// ===================== real kernel: round-9 form (best: 19.4) =====================
__global__ __launch_bounds__(256) void edge_score_fused(
    const float* __restrict__ x,
    const int* __restrict__ edge_index,
    const float* __restrict__ edge_attr,
    const int* __restrict__ edge_mask,
    const float* __restrict__ W1,
    const float* __restrict__ b1,
    const float* __restrict__ W2,
    const float* __restrict__ b2,
    const float* __restrict__ Ws,
    const float* __restrict__ bs,
    float* __restrict__ out, int E)
{
    __shared__ f4 bvS[32];   // per k-pair: (b_lo, b_hi, v_lo, v_hi)
    __shared__ float cS;

    const int t = threadIdx.x;

    {   // fold v = W2@Ws
        const f4* W2v = reinterpret_cast<const f4*>(W2 + t * 16);
        const int j0 = 16 * (t & 3);
        float p = 0.f;
#pragma unroll
        for (int i = 0; i < 4; ++i) {
            const f4 wv = W2v[i];
            const int j = j0 + 4 * i;
            p = fmaf(wv.x, Ws[j], p);
            p = fmaf(wv.y, Ws[j + 1], p);
            p = fmaf(wv.z, Ws[j + 2], p);
            p = fmaf(wv.w, Ws[j + 3], p);
        }
        p += __shfl_xor(p, 1);
        p += __shfl_xor(p, 2);
        if ((t & 3) == 0) {
            const int k = t >> 2;
            reinterpret_cast<float*>(&bvS[k >> 1])[2 + (k & 1)] = p;
        }
    }
    if (t >= 64 && t < 128) {
        const int l = t - 64;
        float p = b2[l] * Ws[l];
#pragma unroll
        for (int off = 1; off < 64; off <<= 1) p += __shfl_xor(p, off);
        if (l == 0) cS = p + bs[0];
    } else if (t >= 192) {
        const int k = t - 192;
        reinterpret_cast<float*>(&bvS[k >> 1])[k & 1] = b1[k];
    }
    __syncthreads();

    const int tid = blockIdx.x * 256 + t;
    const int e = tid * EPT;
    if (e >= E) return;

    const i4 rows = *reinterpret_cast<const i4*>(edge_index + e);
    const i4 cols = *reinterpret_cast<const i4*>(edge_index + E + e);
    const i4 mk   = *reinterpret_cast<const i4*>(edge_mask + e);
    const f4 eaA  = *reinterpret_cast<const f4*>(edge_attr + 2 * e);
    const f4 eaB  = *reinterpret_cast<const f4*>(edge_attr + 2 * e + 4);

    const f2 xr0 = {x[rows.x], x[rows.x]}, xr1 = {x[rows.y], x[rows.y]},
             xr2 = {x[rows.z], x[rows.z]}, xr3 = {x[rows.w], x[rows.w]};
    const f2 xc0 = {x[cols.x], x[cols.x]}, xc1 = {x[cols.y], x[cols.y]},
             xc2 = {x[cols.z], x[cols.z]}, xc3 = {x[cols.w], x[cols.w]};
    const f2 e00 = {eaA.x, eaA.x}, e10 = {eaA.y, eaA.y};
    const f2 e01 = {eaA.z, eaA.z}, e11 = {eaA.w, eaA.w};
    const f2 e02 = {eaB.x, eaB.x}, e12 = {eaB.y, eaB.y};
    const f2 e03 = {eaB.z, eaB.z}, e13 = {eaB.w, eaB.w};

    const float c = cS;
    const f2 z2 = {0.f, 0.f};
    f2 a0 = {c, 0.f}, a1 = {c, 0.f}, a2 = {c, 0.f}, a3 = {c, 0.f};

#pragma unroll 4
    for (int k2 = 0; k2 < 32; ++k2) {
        const f2 w0 = {W1[2 * k2],       W1[2 * k2 + 1]};
        const f2 w1 = {W1[64 + 2 * k2],  W1[64 + 2 * k2 + 1]};
        const f2 w2 = {W1[128 + 2 * k2], W1[128 + 2 * k2 + 1]};
        const f2 w3 = {W1[192 + 2 * k2], W1[192 + 2 * k2 + 1]};
        const f4 C = bvS[k2];
        const f2 bb = {C.x, C.y}, vv = {C.z, C.w};

        f2 h0 = __builtin_elementwise_fma(xr0, w0, __builtin_elementwise_fma(xc0, w1,
                __builtin_elementwise_fma(e00, w2, __builtin_elementwise_fma(e10, w3, bb))));
        f2 h1 = __builtin_elementwise_fma(xr1, w0, __builtin_elementwise_fma(xc1, w1,
                __builtin_elementwise_fma(e01, w2, __builtin_elementwise_fma(e11, w3, bb))));
        f2 h2 = __builtin_elementwise_fma(xr2, w0, __builtin_elementwise_fma(xc2, w1,
                __builtin_elementwise_fma(e02, w2, __builtin_elementwise_fma(e12, w3, bb))));
        f2 h3 = __builtin_elementwise_fma(xr3, w0, __builtin_elementwise_fma(xc3, w1,
                __builtin_elementwise_fma(e03, w2, __builtin_elementwise_fma(e13, w3, bb))));
        a0 = __builtin_elementwise_fma(__builtin_elementwise_max(h0, z2), vv, a0);
        a1 = __builtin_elementwise_fma(__builtin_elementwise_max(h1, z2), vv, a1);
        a2 = __builtin_elementwise_fma(__builtin_elementwise_max(h2, z2), vv, a2);
        a3 = __builtin_elementwise_fma(__builtin_elementwise_max(h3, z2), vv, a3);
    }

    f4 res;
    res.x = mk.x ? (a0.x + a0.y) : MASK_FILL;
    res.y = mk.y ? (a1.x + a1.y) : MASK_FILL;
    res.z = mk.z ? (a2.x + a2.y) : MASK_FILL;
    res.w = mk.w ? (a3.x + a3.y) : MASK_FILL;
    *reinterpret_cast<f4*>(out + e) = res;
}

// ===================== PROBE: memory path only (streams + gathers) =================
// Identical grid and load pattern as the real kernel; zero k-loop. All loaded
// values kept alive via asm sinks (no DCE), NO stores -> output untouched.
// T_probe = dur - 19.4us isolates the memory path's standalone cost.
__global__ __launch_bounds__(256) void probe_mem(
    const float* __restrict__ x,
    const int* __restrict__ edge_index,
    const float* __restrict__ edge_attr,
    const int* __restrict__ edge_mask,
    int E)
{
    const int tid = blockIdx.x * 256 + threadIdx.x;
    const int e = tid * EPT;
    if (e >= E) return;

    const i4 rows = *reinterpret_cast<const i4*>(edge_index + e);
    const i4 cols = *reinterpret_cast<const i4*>(edge_index + E + e);
    const i4 mk   = *reinterpret_cast<const i4*>(edge_mask + e);
    const f4 eaA  = *reinterpret_cast<const f4*>(edge_attr + 2 * e);
    const f4 eaB  = *reinterpret_cast<const f4*>(edge_attr + 2 * e + 4);

    const float g0 = x[rows.x], g1 = x[rows.y], g2 = x[rows.z], g3 = x[rows.w];
    const float h0 = x[cols.x], h1 = x[cols.y], h2 = x[cols.z], h3 = x[cols.w];

    // cheap liveness combine (~20 VALU) + asm sink; no memory writes
    float acc = g0 + g1 + g2 + g3 + h0 + h1 + h2 + h3;
    acc += eaA.x + eaA.y + eaA.z + eaA.w + eaB.x + eaB.y + eaB.z + eaB.w;
    acc += (float)(mk.x + mk.y + mk.z + mk.w);
    asm volatile("" :: "v"(acc));
}

extern "C" void kernel_launch(void* const* d_in, const int* in_sizes, int n_in,
                              void* d_out, int out_size, void* d_ws, size_t ws_size,
                              hipStream_t stream) {
    const float* x          = (const float*)d_in[0];
    const int*   edge_index = (const int*)d_in[1];
    const float* edge_attr  = (const float*)d_in[2];
    const int*   edge_mask  = (const int*)d_in[3];
    const float* W1 = (const float*)d_in[4];
    const float* b1 = (const float*)d_in[5];
    const float* W2 = (const float*)d_in[6];
    const float* b2 = (const float*)d_in[7];
    const float* Ws = (const float*)d_in[8];
    const float* bs = (const float*)d_in[9];
    float* out = (float*)d_out;

    const int E = out_size;  // 1,000,000
    const int threads = 256;
    const int work = (E + EPT - 1) / EPT;
    const int blocks = (work + threads - 1) / threads;

    edge_score_fused<<<blocks, threads, 0, stream>>>(
        x, edge_index, edge_attr, edge_mask, W1, b1, W2, b2, Ws, bs, out, E);
    // appended probe (no output writes): times the bare memory path
    probe_mem<<<blocks, threads, 0, stream>>>(x, edge_index, edge_attr, edge_mask, E);
}

// Round 13
// 19.984 us; speedup vs baseline: 1.3723x; 1.3723x over previous
//
#include <hip/hip_runtime.h>

typedef float f2 __attribute__((ext_vector_type(2)));
typedef float f4 __attribute__((ext_vector_type(4)));
typedef int   i4 __attribute__((ext_vector_type(4)));

#define HIDDEN 64
#define MASK_FILL -1e9f
#define EPT 4   // edges per thread per pipeline stage
#define TPB 256

// scores = relu([x[row], x[col], edge_attr] @ W1 + b1) . v + c
// Round 13: 2-stage software pipeline. Round-12 probe showed mem path (8us)
// and compute (6.5us) run back-to-back with ZERO overlap (lockstep phases).
// Pipeline: streams(1) fly under compute(0); sched_barrier(0) pins issue
// order so the compiler can't cluster loads into one vmcnt(0) drain.
__device__ __forceinline__ f4 kloop_compute(
    const float* __restrict__ W1, const f4* bvS, float c,
    const i4& rows, const i4& cols, const f4& eaA, const f4& eaB,
    const i4& mk, const float* __restrict__ x)
{
    const f2 xr0 = {x[rows.x], x[rows.x]}, xr1 = {x[rows.y], x[rows.y]},
             xr2 = {x[rows.z], x[rows.z]}, xr3 = {x[rows.w], x[rows.w]};
    const f2 xc0 = {x[cols.x], x[cols.x]}, xc1 = {x[cols.y], x[cols.y]},
             xc2 = {x[cols.z], x[cols.z]}, xc3 = {x[cols.w], x[cols.w]};
    const f2 e00 = {eaA.x, eaA.x}, e10 = {eaA.y, eaA.y};
    const f2 e01 = {eaA.z, eaA.z}, e11 = {eaA.w, eaA.w};
    const f2 e02 = {eaB.x, eaB.x}, e12 = {eaB.y, eaB.y};
    const f2 e03 = {eaB.z, eaB.z}, e13 = {eaB.w, eaB.w};

    const f2 z2 = {0.f, 0.f};
    f2 a0 = {c, 0.f}, a1 = {c, 0.f}, a2 = {c, 0.f}, a3 = {c, 0.f};

#pragma unroll 4
    for (int k2 = 0; k2 < 32; ++k2) {
        const f2 w0 = {W1[2 * k2],       W1[2 * k2 + 1]};
        const f2 w1 = {W1[64 + 2 * k2],  W1[64 + 2 * k2 + 1]};
        const f2 w2 = {W1[128 + 2 * k2], W1[128 + 2 * k2 + 1]};
        const f2 w3 = {W1[192 + 2 * k2], W1[192 + 2 * k2 + 1]};
        const f4 C = bvS[k2];
        const f2 bb = {C.x, C.y}, vv = {C.z, C.w};

        f2 h0 = __builtin_elementwise_fma(xr0, w0, __builtin_elementwise_fma(xc0, w1,
                __builtin_elementwise_fma(e00, w2, __builtin_elementwise_fma(e10, w3, bb))));
        f2 h1 = __builtin_elementwise_fma(xr1, w0, __builtin_elementwise_fma(xc1, w1,
                __builtin_elementwise_fma(e01, w2, __builtin_elementwise_fma(e11, w3, bb))));
        f2 h2 = __builtin_elementwise_fma(xr2, w0, __builtin_elementwise_fma(xc2, w1,
                __builtin_elementwise_fma(e02, w2, __builtin_elementwise_fma(e12, w3, bb))));
        f2 h3 = __builtin_elementwise_fma(xr3, w0, __builtin_elementwise_fma(xc3, w1,
                __builtin_elementwise_fma(e03, w2, __builtin_elementwise_fma(e13, w3, bb))));
        a0 = __builtin_elementwise_fma(__builtin_elementwise_max(h0, z2), vv, a0);
        a1 = __builtin_elementwise_fma(__builtin_elementwise_max(h1, z2), vv, a1);
        a2 = __builtin_elementwise_fma(__builtin_elementwise_max(h2, z2), vv, a2);
        a3 = __builtin_elementwise_fma(__builtin_elementwise_max(h3, z2), vv, a3);
    }

    f4 res;
    res.x = mk.x ? (a0.x + a0.y) : MASK_FILL;
    res.y = mk.y ? (a1.x + a1.y) : MASK_FILL;
    res.z = mk.z ? (a2.x + a2.y) : MASK_FILL;
    res.w = mk.w ? (a3.x + a3.y) : MASK_FILL;
    return res;
}

__global__ __launch_bounds__(TPB) void edge_score_fused(
    const float* __restrict__ x,
    const int* __restrict__ edge_index,
    const float* __restrict__ edge_attr,
    const int* __restrict__ edge_mask,
    const float* __restrict__ W1,
    const float* __restrict__ b1,
    const float* __restrict__ W2,
    const float* __restrict__ b2,
    const float* __restrict__ Ws,
    const float* __restrict__ bs,
    float* __restrict__ out, int E)
{
    __shared__ f4 bvS[32];   // per k-pair: (b_lo, b_hi, v_lo, v_hi)
    __shared__ float cS;

    const int t = threadIdx.x;

    {   // fold v = W2@Ws
        const f4* W2v = reinterpret_cast<const f4*>(W2 + t * 16);
        const int j0 = 16 * (t & 3);
        float p = 0.f;
#pragma unroll
        for (int i = 0; i < 4; ++i) {
            const f4 wv = W2v[i];
            const int j = j0 + 4 * i;
            p = fmaf(wv.x, Ws[j], p);
            p = fmaf(wv.y, Ws[j + 1], p);
            p = fmaf(wv.z, Ws[j + 2], p);
            p = fmaf(wv.w, Ws[j + 3], p);
        }
        p += __shfl_xor(p, 1);
        p += __shfl_xor(p, 2);
        if ((t & 3) == 0) {
            const int k = t >> 2;
            reinterpret_cast<float*>(&bvS[k >> 1])[2 + (k & 1)] = p;
        }
    }
    if (t >= 64 && t < 128) {
        const int l = t - 64;
        float p = b2[l] * Ws[l];
#pragma unroll
        for (int off = 1; off < 64; off <<= 1) p += __shfl_xor(p, off);
        if (l == 0) cS = p + bs[0];
    } else if (t >= 192) {
        const int k = t - 192;
        reinterpret_cast<float*>(&bvS[k >> 1])[k & 1] = b1[k];
    }
    __syncthreads();

    const float c = cS;
    const int TOT4 = (int)gridDim.x * TPB * EPT;       // edges per stage
    const int e0 = (blockIdx.x * TPB + t) * EPT;       // always < TOT4 <= E
    const int e1 = e0 + TOT4;
    const bool v1 = e1 < E;
    const int ec1 = v1 ? e1 : 0;

    // ---- stage-0 streams ----
    const i4 rows0 = *reinterpret_cast<const i4*>(edge_index + e0);
    const i4 cols0 = *reinterpret_cast<const i4*>(edge_index + E + e0);
    const i4 mk0   = *reinterpret_cast<const i4*>(edge_mask + e0);
    const f4 eaA0  = *reinterpret_cast<const f4*>(edge_attr + 2 * e0);
    const f4 eaB0  = *reinterpret_cast<const f4*>(edge_attr + 2 * e0 + 4);

    // ---- stage-0 gathers (dep on rows0/cols0 -> waits streams0 only) ----
    const float g0 = x[rows0.x], g1 = x[rows0.y], g2 = x[rows0.z], g3 = x[rows0.w];
    const float h0 = x[cols0.x], h1 = x[cols0.y], h2 = x[cols0.z], h3 = x[cols0.w];
    asm volatile("" :: "v"(g0), "v"(g1), "v"(g2), "v"(g3),
                       "v"(h0), "v"(h1), "v"(h2), "v"(h3));
    __builtin_amdgcn_sched_barrier(0);   // gathers0 issued before streams1

    // ---- stage-1 streams (fly under compute0) ----
    const i4 rows1 = *reinterpret_cast<const i4*>(edge_index + ec1);
    const i4 cols1 = *reinterpret_cast<const i4*>(edge_index + E + ec1);
    const i4 mk1   = *reinterpret_cast<const i4*>(edge_mask + ec1);
    const f4 eaA1  = *reinterpret_cast<const f4*>(edge_attr + 2 * ec1);
    const f4 eaB1  = *reinterpret_cast<const f4*>(edge_attr + 2 * ec1 + 4);
    __builtin_amdgcn_sched_barrier(0);   // streams1 issued before compute0

    // ---- compute stage 0 (vmcnt waits gathers0; streams1 outstanding) ----
    {
        const f2 xr0 = {g0, g0}, xr1 = {g1, g1}, xr2 = {g2, g2}, xr3 = {g3, g3};
        const f2 xc0 = {h0, h0}, xc1 = {h1, h1}, xc2 = {h2, h2}, xc3 = {h3, h3};
        const f2 e00 = {eaA0.x, eaA0.x}, e10 = {eaA0.y, eaA0.y};
        const f2 e01 = {eaA0.z, eaA0.z}, e11 = {eaA0.w, eaA0.w};
        const f2 e02 = {eaB0.x, eaB0.x}, e12 = {eaB0.y, eaB0.y};
        const f2 e03 = {eaB0.z, eaB0.z}, e13 = {eaB0.w, eaB0.w};
        const f2 z2 = {0.f, 0.f};
        f2 a0 = {c, 0.f}, a1 = {c, 0.f}, a2 = {c, 0.f}, a3 = {c, 0.f};
#pragma unroll 4
        for (int k2 = 0; k2 < 32; ++k2) {
            const f2 w0 = {W1[2 * k2],       W1[2 * k2 + 1]};
            const f2 w1 = {W1[64 + 2 * k2],  W1[64 + 2 * k2 + 1]};
            const f2 w2 = {W1[128 + 2 * k2], W1[128 + 2 * k2 + 1]};
            const f2 w3 = {W1[192 + 2 * k2], W1[192 + 2 * k2 + 1]};
            const f4 C = bvS[k2];
            const f2 bb = {C.x, C.y}, vv = {C.z, C.w};
            f2 q0 = __builtin_elementwise_fma(xr0, w0, __builtin_elementwise_fma(xc0, w1,
                    __builtin_elementwise_fma(e00, w2, __builtin_elementwise_fma(e10, w3, bb))));
            f2 q1 = __builtin_elementwise_fma(xr1, w0, __builtin_elementwise_fma(xc1, w1,
                    __builtin_elementwise_fma(e01, w2, __builtin_elementwise_fma(e11, w3, bb))));
            f2 q2 = __builtin_elementwise_fma(xr2, w0, __builtin_elementwise_fma(xc2, w1,
                    __builtin_elementwise_fma(e02, w2, __builtin_elementwise_fma(e12, w3, bb))));
            f2 q3 = __builtin_elementwise_fma(xr3, w0, __builtin_elementwise_fma(xc3, w1,
                    __builtin_elementwise_fma(e03, w2, __builtin_elementwise_fma(e13, w3, bb))));
            a0 = __builtin_elementwise_fma(__builtin_elementwise_max(q0, z2), vv, a0);
            a1 = __builtin_elementwise_fma(__builtin_elementwise_max(q1, z2), vv, a1);
            a2 = __builtin_elementwise_fma(__builtin_elementwise_max(q2, z2), vv, a2);
            a3 = __builtin_elementwise_fma(__builtin_elementwise_max(q3, z2), vv, a3);
        }
        f4 res;
        res.x = mk0.x ? (a0.x + a0.y) : MASK_FILL;
        res.y = mk0.y ? (a1.x + a1.y) : MASK_FILL;
        res.z = mk0.z ? (a2.x + a2.y) : MASK_FILL;
        res.w = mk0.w ? (a3.x + a3.y) : MASK_FILL;
        *reinterpret_cast<f4*>(out + e0) = res;
    }

    // ---- stage 1: gathers (streams1 returned during compute0) + compute ----
    const f4 res1 = kloop_compute(W1, bvS, c, rows1, cols1, eaA1, eaB1, mk1, x);
    if (v1) *reinterpret_cast<f4*>(out + e1) = res1;
}

extern "C" void kernel_launch(void* const* d_in, const int* in_sizes, int n_in,
                              void* d_out, int out_size, void* d_ws, size_t ws_size,
                              hipStream_t stream) {
    const float* x          = (const float*)d_in[0];
    const int*   edge_index = (const int*)d_in[1];
    const float* edge_attr  = (const float*)d_in[2];
    const int*   edge_mask  = (const int*)d_in[3];
    const float* W1 = (const float*)d_in[4];
    const float* b1 = (const float*)d_in[5];
    const float* W2 = (const float*)d_in[6];
    const float* b2 = (const float*)d_in[7];
    const float* Ws = (const float*)d_in[8];
    const float* bs = (const float*)d_in[9];
    float* out = (float*)d_out;

    const int E = out_size;                    // 1,000,000
    // 2 stages: blocks sized so 2 * blocks * TPB * EPT >= E
    const int stage_edges = (E + 1) / 2;
    const int blocks = (stage_edges + TPB * EPT - 1) / (TPB * EPT);   // 489
    edge_score_fused<<<blocks, TPB, 0, stream>>>(
        x, edge_index, edge_attr, edge_mask, W1, b1, W2, b2, Ws, bs, out, E);
}